// Round 3
// baseline (541.405 us; speedup 1.0000x reference)
//
#include <hip/hip_runtime.h>
#include <hip/hip_bf16.h>

#define N_PTS 12288
#define DIM   64
#define KSEL  16
#define EPS_F 1e-5f
#define CAP   12     // per-lane-per-list LDS candidate buffer depth
#define NFIN  32     // finalists per row handed to fp64 refine

typedef __bf16 bf16x8 __attribute__((ext_vector_type(8)));
typedef float  f32x4  __attribute__((ext_vector_type(4)));

// ---------------------------------------------------------------------------
// Kernel A: fp32 row norms sq[i] (screen), fp64 row norms sq64[i] (refine),
// S1 = sum(sq), Sx[d] = column sums (closed-form sigma2), and a bf16 copy of
// coords for the MFMA screen. One wave per 16 rows; lane = dimension d.
// ---------------------------------------------------------------------------
__global__ void stats_kernel(const float* __restrict__ coords,
                             double* __restrict__ sq64,
                             float* __restrict__ sq,
                             float* __restrict__ s1,
                             float* __restrict__ sx,
                             __hip_bfloat16* __restrict__ chi)
{
    const int lane = threadIdx.x & 63;
    const int gw   = (blockIdx.x * blockDim.x + threadIdx.x) >> 6;
    const int r0   = gw * 16;
    float colsum = 0.f, sqsum = 0.f;
    for (int rr = 0; rr < 16; ++rr) {
        const int r = r0 + rr;
        const float x = coords[r * DIM + lane];
        chi[r * DIM + lane] = __float2bfloat16(x);
        colsum += x;
        float  p  = x * x;
        double p64 = (double)x * (double)x;
        #pragma unroll
        for (int off = 32; off > 0; off >>= 1) {
            p   += __shfl_xor(p, off, 64);
            p64 += __shfl_xor(p64, off, 64);
        }
        if (lane == 0) { sq[r] = p; sq64[r] = p64; sqsum += p; }
    }
    atomicAdd(&sx[lane], colsum);
    if (lane == 0) atomicAdd(s1, sqsum);
}

// Branchless insert of (c, ci) into a descending-sorted 16-list (v[0] = max).
// Caller guarantees c < v[0].
__device__ __forceinline__ void insert16(float (&v)[KSEL], int (&id)[KSEL],
                                         float c, int ci)
{
    #pragma unroll
    for (int t = 0; t < KSEL - 1; ++t) {
        const bool shift = (v[t + 1] > c);
        const bool place = (!shift) && (v[t] > c);
        const float nv = shift ? v[t + 1] : (place ? c : v[t]);
        const int   ni = shift ? id[t + 1] : (place ? ci : id[t]);
        v[t] = nv; id[t] = ni;
    }
    if (v[KSEL - 1] > c) { v[KSEL - 1] = c; id[KSEL - 1] = ci; }
}

__device__ __forceinline__ void flushbuf(const float* bv, const int* bi,
                                         int cnt, float (&v)[KSEL], int (&id)[KSEL])
{
    #pragma unroll 1
    for (int p = 0; p < CAP; ++p) {
        if (p < cnt) {
            const float c = bv[p];
            if (c < v[0]) insert16(v, id, c, bi[p]);
        }
    }
}

// ---------------------------------------------------------------------------
// Kernel B: bf16-MFMA screened dist2 + top-16-per-substream, merge to 32
// finalists/row, fp64-exact refine + rank-16 + laplacian (fp64), fp32 out.
// Block = 256 threads / 4 waves, owns a 32-row i-tile (two top-16 lists per
// lane). Each wave scans one j-quarter in 16-wide MFMA steps.
// ---------------------------------------------------------------------------
__global__ __launch_bounds__(256) void knn_lap_kernel(
    const float* __restrict__ coords,
    const float* __restrict__ pot,
    const float* __restrict__ sq,
    const double* __restrict__ sq64,
    const float* __restrict__ s1,
    const float* __restrict__ sx,
    const __hip_bfloat16* __restrict__ chi,
    float* __restrict__ out)
{
    __shared__ double s_sigma;
    __shared__ __align__(16) char smem[71680];
    // scan phase: per-thread candidate buffers (49152 B used)
    float* bufv = (float*)smem;                        // [256*2*CAP]
    int*   bufi = (int*)(smem + 256 * 2 * CAP * 4);    // [256*2*CAP]
    // merge phase (aliases scan bufs, after barrier): 32 rows x 256 cands
    float*  mval = (float*)smem;                       // [8192]
    int*    midx = (int*)(smem + 32768);               // [8192]
    int*    finj = (int*)(smem + 65536);               // [32*NFIN]
    double* refv = (double*)(smem + 65536 + 32 * NFIN * 4); // [256] fp64 d2

    const int tid  = threadIdx.x;
    const int lane = tid & 63;
    const int wave = tid >> 6;
    const int col  = lane & 15;
    const int quad = lane >> 4;
    const int ibase = (int)blockIdx.x * 32;
    const int i0 = ibase + col;        // list 0's row
    const int i1 = ibase + 16 + col;   // list 1's row

    if (tid == 0) {
        // sigma2 = mean(dist2 incl. +eps everywhere and +1e6 on the diagonal)
        double S1 = (double)s1[0], m2 = 0.0;
        for (int d = 0; d < DIM; ++d) { double t = (double)sx[d]; m2 += t * t; }
        const double NN = (double)N_PTS;
        s_sigma = (2.0 * NN * S1 - 2.0 * m2) / (NN * NN) + 1e-5 + 1e6 / NN;
    }

    // B fragments (bf16): lane holds n = col, k = quad*8+jj (+32 for *1)
    const bf16x8* cp = (const bf16x8*)chi;   // 8 bf16 per chunk, 8 chunks/row
    const bf16x8 b00 = cp[i0 * 8 + quad], b01 = cp[i0 * 8 + quad + 4];
    const bf16x8 b10 = cp[i1 * 8 + quad], b11 = cp[i1 * 8 + quad + 4];
    const float base0 = sq[i0] + EPS_F;
    const float base1 = sq[i1] + EPS_F;

    float v0[KSEL], v1[KSEL]; int id0[KSEL], id1[KSEL];
    #pragma unroll
    for (int t = 0; t < KSEL; ++t) {
        v0[t] = 1e30f; v1[t] = 1e30f; id0[t] = 0; id1[t] = 0;
    }

    int c0 = 0, c1 = 0;
    const int jw = wave * (N_PTS / 4);
    for (int s = 0; s < (N_PTS / 4) / 16; ++s) {
        const int j0 = jw + s * 16;
        const int arow = j0 + col;     // lane's A-row m = col
        const bf16x8 a0 = cp[arow * 8 + quad];
        const bf16x8 a1 = cp[arow * 8 + quad + 4];
        f32x4 acc0 = {0.f, 0.f, 0.f, 0.f};
        acc0 = __builtin_amdgcn_mfma_f32_16x16x32_bf16(a0, b00, acc0, 0, 0, 0);
        acc0 = __builtin_amdgcn_mfma_f32_16x16x32_bf16(a1, b01, acc0, 0, 0, 0);
        f32x4 acc1 = {0.f, 0.f, 0.f, 0.f};
        acc1 = __builtin_amdgcn_mfma_f32_16x16x32_bf16(a0, b10, acc1, 0, 0, 0);
        acc1 = __builtin_amdgcn_mfma_f32_16x16x32_bf16(a1, b11, acc1, 0, 0, 0);

        const float4 sqj = *(const float4*)(sq + j0 + quad * 4);
        const int    jq  = j0 + quad * 4;
        #pragma unroll
        for (int r = 0; r < 4; ++r) {
            const float sj = (r == 0) ? sqj.x : (r == 1) ? sqj.y
                           : (r == 2) ? sqj.z : sqj.w;
            const int j = jq + r;
            float d2a = base0 + sj - 2.0f * acc0[r];
            float d2b = base1 + sj - 2.0f * acc1[r];
            if (j == i0) d2a = 1e30f;          // exclude self
            if (j == i1) d2b = 1e30f;
            if (d2a < v0[0]) {
                bufv[(tid * 2 + 0) * CAP + c0] = d2a;
                bufi[(tid * 2 + 0) * CAP + c0] = j; ++c0;
            }
            if (d2b < v1[0]) {
                bufv[(tid * 2 + 1) * CAP + c1] = d2b;
                bufi[(tid * 2 + 1) * CAP + c1] = j; ++c1;
            }
        }
        const int cmax = (c0 > c1) ? c0 : c1;
        if (__any(cmax >= CAP - 3)) {          // drain all lanes in parallel
            flushbuf(bufv + (tid * 2 + 0) * CAP, bufi + (tid * 2 + 0) * CAP, c0, v0, id0);
            flushbuf(bufv + (tid * 2 + 1) * CAP, bufi + (tid * 2 + 1) * CAP, c1, v1, id1);
            c0 = 0; c1 = 0;
        }
    }
    flushbuf(bufv + (tid * 2 + 0) * CAP, bufi + (tid * 2 + 0) * CAP, c0, v0, id0);
    flushbuf(bufv + (tid * 2 + 1) * CAP, bufi + (tid * 2 + 1) * CAP, c1, v1, id1);

    __syncthreads();   // scan buffers dead; reuse LDS for the merge
    const int slot = wave * 4 + quad;          // 16 contributors per row
    #pragma unroll
    for (int t = 0; t < KSEL; ++t) {
        mval[(col)      * 256 + slot * KSEL + t] = v0[t];
        midx[(col)      * 256 + slot * KSEL + t] = id0[t];
        mval[(16 + col) * 256 + slot * KSEL + t] = v1[t];
        midx[(16 + col) * 256 + slot * KSEL + t] = id1[t];
    }
    __syncthreads();

    // Extract approx-top-32 finalists per row (wave w owns rows 8w..8w+7).
    for (int rr = 0; rr < 8; ++rr) {
        const int row = wave * 8 + rr;
        float lv[4]; int li[4];
        #pragma unroll
        for (int t = 0; t < 4; ++t) {
            lv[t] = mval[row * 256 + lane * 4 + t];
            li[t] = midx[row * 256 + lane * 4 + t];
        }
        #pragma unroll 1
        for (int k = 0; k < NFIN; ++k) {
            float bm = lv[0]; int bi = li[0]; int bp = lane * 4;
            #pragma unroll
            for (int t = 1; t < 4; ++t)
                if (lv[t] < bm) { bm = lv[t]; bi = li[t]; bp = lane * 4 + t; }
            #pragma unroll
            for (int off = 1; off < 64; off <<= 1) {
                const float ov = __shfl_xor(bm, off, 64);
                const int   oi = __shfl_xor(bi, off, 64);
                const int   op = __shfl_xor(bp, off, 64);
                if (ov < bm || (ov == bm && op < bp)) { bm = ov; bi = oi; bp = op; }
            }
            if (lane == 0) finj[row * NFIN + k] = bi;
            if ((bp >> 2) == lane) {
                const int t2 = bp & 3;
                #pragma unroll
                for (int t = 0; t < 4; ++t) if (t == t2) lv[t] = 1e30f;
            }
        }
    }
    __syncthreads();

    // fp64 refine of the 32 finalists + rank-select 16 + fp64 laplacian.
    // Half-wave per row: lane = (h<<5) | l, l = finalist index.
    const double inv_den = 1.0 / (s_sigma + 1e-5);
    const int h = lane >> 5;
    const int l = lane & 31;
    for (int rp = 0; rp < 4; ++rp) {
        const int rowL = wave * 8 + rp * 2 + h;
        const int i = ibase + rowL;
        const int j = finj[rowL * NFIN + l];
        const float4* xi = (const float4*)(coords + i * DIM);
        const float4* xj = (const float4*)(coords + j * DIM);
        double dot = 0.0;
        #pragma unroll
        for (int q = 0; q < DIM / 4; ++q) {
            const float4 a = xi[q], b = xj[q];
            dot += (double)a.x * (double)b.x + (double)a.y * (double)b.y
                 + (double)a.z * (double)b.z + (double)a.w * (double)b.w;
        }
        const double d2 = sq64[i] + sq64[j] + 1e-5 - 2.0 * dot;
        refv[tid] = d2;
        __syncthreads();
        int rank = 0;
        #pragma unroll 1
        for (int m = 0; m < NFIN; ++m) {
            const double o = refv[wave * 64 + h * 32 + m];
            rank += (o < d2 || (o == d2 && m < l)) ? 1 : 0;
        }
        const double w = exp(-d2 * inv_den);
        double contrib = (rank < KSEL)
                       ? w * ((double)pot[j] - (double)pot[i]) : 0.0;
        #pragma unroll
        for (int off = 1; off < 32; off <<= 1)
            contrib += __shfl_xor(contrib, off, 64);
        if (l == 0) out[i] = (float)contrib;
        __syncthreads();
    }
}

extern "C" void kernel_launch(void* const* d_in, const int* in_sizes, int n_in,
                              void* d_out, int out_size, void* d_ws, size_t ws_size,
                              hipStream_t stream)
{
    (void)in_sizes; (void)n_in; (void)out_size; (void)ws_size;
    const float* coords = (const float*)d_in[0];
    const float* pot    = (const float*)d_in[1];
    // d_in[2] is k (always 16, compiled in as KSEL)

    char* w = (char*)d_ws;
    double* sq64 = (double*)w;                        // [N_PTS]  (8-aligned)
    float*  sq   = (float*)(w + N_PTS * 8);           // [N_PTS]
    float*  s1   = (float*)(w + N_PTS * 12);          // [1]
    float*  sx   = (float*)(w + N_PTS * 12 + 4);      // [DIM]
    __hip_bfloat16* chi =
        (__hip_bfloat16*)(w + ((N_PTS * 12 + 4 + DIM * 4 + 15) & ~15)); // [N*DIM]

    hipMemsetAsync((void*)s1, 0, (1 + DIM) * sizeof(float), stream);
    stats_kernel<<<dim3(N_PTS / 64), dim3(256), 0, stream>>>(
        coords, sq64, sq, s1, sx, chi);
    knn_lap_kernel<<<dim3(N_PTS / 32), dim3(256), 0, stream>>>(
        coords, pot, sq, sq64, s1, sx, chi, (float*)d_out);
}

// Round 4
// 275.440 us; speedup vs baseline: 1.9656x; 1.9656x over previous
//
#include <hip/hip_runtime.h>
#include <hip/hip_bf16.h>

#define N_PTS 12288
#define DIM   64
#define KSEL  16
#define EPS_F 1e-5f
#define CAPB  10    // per-lane-per-list LDS candidate buffer depth
#define XTR   24    // per-(row,chunk) survivors handed to the merge kernel

typedef __bf16 bf16x8 __attribute__((ext_vector_type(8)));
typedef float  f32x4  __attribute__((ext_vector_type(4)));

// ---------------------------------------------------------------------------
// Kernel A: fp32 row norms sq[i], S1 = sum(sq), Sx[d] = column sums (for the
// closed-form sigma2), and a bf16 copy of coords for the MFMA screen.
// Grid 256 x 256 thr: 1024 waves, each wave strides 12 rows; lane = dim.
// ---------------------------------------------------------------------------
__global__ __launch_bounds__(256) void stats_kernel(
    const float* __restrict__ coords,
    float* __restrict__ sq,
    float* __restrict__ s1,
    float* __restrict__ sx,
    __hip_bfloat16* __restrict__ chi)
{
    __shared__ float colsh[4][64];
    const int lane = threadIdx.x & 63;
    const int wave = threadIdx.x >> 6;
    const int gw   = blockIdx.x * 4 + wave;     // 0..1023
    float colsum = 0.f, sqsum = 0.f;
    for (int r = gw; r < N_PTS; r += 1024) {
        const float x = coords[r * DIM + lane];
        chi[r * DIM + lane] = __float2bfloat16(x);
        colsum += x;
        float p = x * x;
        #pragma unroll
        for (int off = 32; off > 0; off >>= 1)
            p += __shfl_xor(p, off, 64);
        if (lane == 0) { sq[r] = p; sqsum += p; }
    }
    colsh[wave][lane] = colsum;
    __syncthreads();
    if (wave == 0) {
        const float c = colsh[0][lane] + colsh[1][lane]
                      + colsh[2][lane] + colsh[3][lane];
        atomicAdd(&sx[lane], c);
    }
    if (lane == 0) atomicAdd(s1, sqsum);
}

// Branchless insert of packed word c into a descending-sorted 8-list
// (v[0] = max = screen threshold). Caller guarantees c < v[0].
__device__ __forceinline__ void insert8(unsigned (&v)[8], unsigned c)
{
    #pragma unroll
    for (int t = 0; t < 7; ++t) {
        const bool shift = (v[t + 1] > c);
        const bool place = (!shift) && (v[t] > c);
        v[t] = shift ? v[t + 1] : (place ? c : v[t]);
    }
    if (v[7] > c) v[7] = c;
}

__device__ __forceinline__ void drain(const unsigned* buf, int cnt,
                                      unsigned (&v)[8], int tid)
{
    #pragma unroll 1
    for (int p = 0; p < CAPB; ++p) {
        if (p < cnt) {
            const unsigned c = buf[p * 256 + tid];
            if (c < v[0]) insert8(v, c);
        }
    }
}

// ---------------------------------------------------------------------------
// Kernel B (scan): bf16-MFMA dist2 over one j-chunk, per-lane top-8 packed
// (d2-quantized<<14 | j) with pooled-quad threshold, per-(row,chunk) top-24
// out to global ws. Block = 256 thr / 4 waves, 32 i-rows; wave scans a
// quarter of the chunk. Packed uint order == (d2 quantized, j asc).
// ---------------------------------------------------------------------------
template<int CHUNKS>
__global__ __launch_bounds__(256) void scan_kernel(
    const float* __restrict__ sq,
    const __hip_bfloat16* __restrict__ chi,
    unsigned* __restrict__ wsknn)            // [N][CHUNKS][XTR]
{
    // scan buffers (2*CAPB*256 = 5120 u32) alias merge rows (32*129 = 4128)
    __shared__ __align__(16) unsigned smem[5120];

    const int tid  = threadIdx.x;
    const int lane = tid & 63;
    const int wave = tid >> 6;
    const int col  = lane & 15;
    const int quad = lane >> 4;
    const int ibase = (int)blockIdx.x * 32;
    const int i0 = ibase + col;
    const int i1 = ibase + 16 + col;

    const bf16x8* cp = (const bf16x8*)chi;
    const bf16x8 b00 = cp[i0 * 8 + quad], b01 = cp[i0 * 8 + quad + 4];
    const bf16x8 b10 = cp[i1 * 8 + quad], b11 = cp[i1 * 8 + quad + 4];
    const float base0 = sq[i0] + EPS_F;
    const float base1 = sq[i1] + EPS_F;

    unsigned v0[8], v1[8];
    #pragma unroll
    for (int t = 0; t < 8; ++t) { v0[t] = 0xFFFFFFFFu; v1[t] = 0xFFFFFFFFu; }

    unsigned* buf0 = smem;
    unsigned* buf1 = smem + CAPB * 256;
    int c0 = 0, c1 = 0;

    const int chunk = (int)blockIdx.y;
    const int jw = chunk * (N_PTS / CHUNKS) + wave * (N_PTS / CHUNKS / 4);
    const int STEPS = N_PTS / CHUNKS / 64;

    #pragma unroll 1
    for (int s = 0; s < STEPS; ++s) {
        const int j0 = jw + s * 16;
        const int arow = j0 + col;
        const bf16x8 a0 = cp[arow * 8 + quad];
        const bf16x8 a1 = cp[arow * 8 + quad + 4];
        f32x4 acc0 = {0.f, 0.f, 0.f, 0.f};
        acc0 = __builtin_amdgcn_mfma_f32_16x16x32_bf16(a0, b00, acc0, 0, 0, 0);
        acc0 = __builtin_amdgcn_mfma_f32_16x16x32_bf16(a1, b01, acc0, 0, 0, 0);
        f32x4 acc1 = {0.f, 0.f, 0.f, 0.f};
        acc1 = __builtin_amdgcn_mfma_f32_16x16x32_bf16(a0, b10, acc1, 0, 0, 0);
        acc1 = __builtin_amdgcn_mfma_f32_16x16x32_bf16(a1, b11, acc1, 0, 0, 0);

        // pooled threshold: max over quads of v[4] upper-bounds the row-pool
        // 16th smallest -> c >= T provably cannot be in the row's top-16.
        unsigned T0 = v0[4], T1 = v1[4];
        { unsigned t = __shfl_xor(T0, 16, 64); T0 = T0 > t ? T0 : t;
          t = __shfl_xor(T0, 32, 64); T0 = T0 > t ? T0 : t; }
        { unsigned t = __shfl_xor(T1, 16, 64); T1 = T1 > t ? T1 : t;
          t = __shfl_xor(T1, 32, 64); T1 = T1 > t ? T1 : t; }

        const float4 sqj = *(const float4*)(sq + j0 + quad * 4);
        const int    jq  = j0 + quad * 4;
        #pragma unroll
        for (int r = 0; r < 4; ++r) {
            const float sj = (r == 0) ? sqj.x : (r == 1) ? sqj.y
                           : (r == 2) ? sqj.z : sqj.w;
            const int j = jq + r;
            const float d2a = base0 + sj - 2.0f * acc0[r];
            const float d2b = base1 + sj - 2.0f * acc1[r];
            const unsigned pa = (__float_as_uint(d2a) & 0xFFFFC000u) | (unsigned)j;
            const unsigned pb = (__float_as_uint(d2b) & 0xFFFFC000u) | (unsigned)j;
            if (j != i0 && pa < v0[0] && pa < T0) { buf0[c0 * 256 + tid] = pa; ++c0; }
            if (j != i1 && pb < v1[0] && pb < T1) { buf1[c1 * 256 + tid] = pb; ++c1; }
        }
        const int cmax = (c0 > c1) ? c0 : c1;
        if (__any(cmax >= CAPB - 4)) {
            drain(buf0, c0, v0, tid);
            drain(buf1, c1, v1, tid);
            c0 = 0; c1 = 0;
        }
    }
    drain(buf0, c0, v0, tid);
    drain(buf1, c1, v1, tid);

    __syncthreads();                 // scan buffers dead; alias as merge rows
    unsigned* mrow = smem;           // [32][129] (+1 pad: 2-way banks only)
    const int slot = wave * 4 + quad;
    #pragma unroll
    for (int t = 0; t < 8; ++t) {
        mrow[col * 129 + slot * 8 + t]        = v0[t];
        mrow[(16 + col) * 129 + slot * 8 + t] = v1[t];
    }
    __syncthreads();

    // Extract the 24 smallest of each row's 128 survivors (wave w: rows 8w..).
    #pragma unroll 1
    for (int rr = 0; rr < 8; ++rr) {
        const int row = wave * 8 + rr;
        unsigned lv0 = mrow[row * 129 + lane * 2];
        unsigned lv1 = mrow[row * 129 + lane * 2 + 1];
        unsigned keep = 0xFFFFFFFFu;
        #pragma unroll 1
        for (int k = 0; k < XTR; ++k) {
            unsigned m = lv0 < lv1 ? lv0 : lv1;
            #pragma unroll
            for (int off = 1; off < 64; off <<= 1) {
                const unsigned o = __shfl_xor(m, off, 64);
                m = o < m ? o : m;
            }
            if (lane == k) keep = m;
            if (lv0 == m) lv0 = 0xFFFFFFFFu;   // values unique (j embedded)
            if (lv1 == m) lv1 = 0xFFFFFFFFu;
        }
        if (lane < XTR)
            wsknn[((ibase + row) * CHUNKS + chunk) * XTR + lane] = keep;
    }
}

// ---------------------------------------------------------------------------
// Kernel C (merge): pool CHUNKS*24 survivors/row, top-32 by screen value,
// fp64-exact refine + rank-16 + fp64 laplacian, fp32 out.
// Block 256 thr = 8 half-waves = 8 rows; grid N/8.
// ---------------------------------------------------------------------------
template<int CHUNKS>
__global__ __launch_bounds__(256) void merge_kernel(
    const float* __restrict__ coords,
    const float* __restrict__ pot,
    const float* __restrict__ s1,
    const float* __restrict__ sx,
    const unsigned* __restrict__ wsknn,
    float* __restrict__ out)
{
    constexpr int POOL = CHUNKS * XTR;
    constexpr int NF   = POOL < 32 ? POOL : 32;
    __shared__ double   s_inv_den;
    __shared__ unsigned allv[8][POOL];
    __shared__ int      finj[8][32];
    __shared__ double   refd[8][32];

    const int tid = threadIdx.x;
    const int hw  = tid >> 5;          // half-wave id = local row
    const int l   = tid & 31;
    const int row = (int)blockIdx.x * 8 + hw;

    if (tid == 0) {
        // sigma2 = mean(dist2 incl. +eps everywhere and +1e6 on the diagonal)
        double S1 = (double)s1[0], m2 = 0.0;
        for (int d = 0; d < DIM; ++d) { double t = (double)sx[d]; m2 += t * t; }
        const double NN = (double)N_PTS;
        s_inv_den = 1.0 / ((2.0 * NN * S1 - 2.0 * m2) / (NN * NN)
                           + 1e-5 + 1e6 / NN + 1e-5);
    }
    for (int t = l; t < POOL; t += 32)
        allv[hw][t] = wsknn[row * POOL + t];
    __syncthreads();

    // rank-select the NF smallest (values unique -> rank is a bijection)
    for (int t = l; t < POOL; t += 32) {
        const unsigned c = allv[hw][t];
        int rank = 0;
        #pragma unroll 4
        for (int m = 0; m < POOL; ++m) rank += (allv[hw][m] < c) ? 1 : 0;
        if (rank < NF) finj[hw][rank] = (int)(c & 0x3FFFu);
    }
    __syncthreads();

    // fp64 refine (dot + both norms in one pass) + rank-16 + laplacian
    const double inv_den = s_inv_den;
    const int j = (l < NF) ? finj[hw][l] : row;
    const float4* xi = (const float4*)(coords + row * DIM);
    const float4* xj = (const float4*)(coords + j * DIM);
    double dot = 0.0, sqi = 0.0, sqj = 0.0;
    #pragma unroll
    for (int q = 0; q < DIM / 4; ++q) {
        const float4 a = xi[q], b = xj[q];
        dot += (double)a.x * (double)b.x + (double)a.y * (double)b.y
             + (double)a.z * (double)b.z + (double)a.w * (double)b.w;
        sqi += (double)a.x * (double)a.x + (double)a.y * (double)a.y
             + (double)a.z * (double)a.z + (double)a.w * (double)a.w;
        sqj += (double)b.x * (double)b.x + (double)b.y * (double)b.y
             + (double)b.z * (double)b.z + (double)b.w * (double)b.w;
    }
    double d2 = sqi + sqj + 1e-5 - 2.0 * dot;
    if (l >= NF) d2 = 1e300;
    refd[hw][l] = d2;
    __syncthreads();

    int rank = 0;
    #pragma unroll 1
    for (int m = 0; m < 32; ++m) {
        const double o = refd[hw][m];
        rank += (o < d2 || (o == d2 && m < l)) ? 1 : 0;
    }
    const double w = exp(-d2 * inv_den);
    double contrib = (rank < KSEL && l < NF)
                   ? w * ((double)pot[j] - (double)pot[row]) : 0.0;
    #pragma unroll
    for (int off = 1; off < 32; off <<= 1)
        contrib += __shfl_xor(contrib, off, 64);
    if (l == 0) out[row] = (float)contrib;
}

extern "C" void kernel_launch(void* const* d_in, const int* in_sizes, int n_in,
                              void* d_out, int out_size, void* d_ws, size_t ws_size,
                              hipStream_t stream)
{
    (void)in_sizes; (void)n_in; (void)out_size;
    const float* coords = (const float*)d_in[0];
    const float* pot    = (const float*)d_in[1];
    // d_in[2] is k (always 16, compiled in as KSEL)

    char* w = (char*)d_ws;
    float* sq = (float*)w;                             // [N_PTS]      49152 B
    float* s1 = (float*)(w + 49152);                   // [1]
    float* sx = (float*)(w + 49156);                   // [DIM]
    __hip_bfloat16* chi = (__hip_bfloat16*)(w + 49424);// [N*DIM] bf16 1.57 MB
    unsigned* wsknn = (unsigned*)(w + 1622288);        // [N][C][XTR]

    const size_t need4 = 1622288 + (size_t)N_PTS * 4 * XTR * 4;  // 6.34 MB
    const size_t need2 = 1622288 + (size_t)N_PTS * 2 * XTR * 4;  // 3.98 MB

    hipMemsetAsync((void*)s1, 0, (1 + DIM) * sizeof(float), stream);
    stats_kernel<<<dim3(256), dim3(256), 0, stream>>>(coords, sq, s1, sx, chi);

    if (ws_size >= need4) {
        scan_kernel<4><<<dim3(N_PTS / 32, 4), dim3(256), 0, stream>>>(sq, chi, wsknn);
        merge_kernel<4><<<dim3(N_PTS / 8), dim3(256), 0, stream>>>(
            coords, pot, s1, sx, wsknn, (float*)d_out);
    } else if (ws_size >= need2) {
        scan_kernel<2><<<dim3(N_PTS / 32, 2), dim3(256), 0, stream>>>(sq, chi, wsknn);
        merge_kernel<2><<<dim3(N_PTS / 8), dim3(256), 0, stream>>>(
            coords, pot, s1, sx, wsknn, (float*)d_out);
    } else {
        scan_kernel<1><<<dim3(N_PTS / 32, 1), dim3(256), 0, stream>>>(sq, chi, wsknn);
        merge_kernel<1><<<dim3(N_PTS / 8), dim3(256), 0, stream>>>(
            coords, pot, s1, sx, wsknn, (float*)d_out);
    }
}